// Round 6
// baseline (187.445 us; speedup 1.0000x reference)
//
#include <hip/hip_runtime.h>
#include <math.h>

#define TK 30
#define TH 128
#define TNIN 256
#define TDFF 512
#define NTOK 8000
#define MROWS 240000   // NTOK*TK

typedef __attribute__((ext_vector_type(8))) short short8v;
typedef __attribute__((ext_vector_type(4))) short short4v;
typedef __attribute__((ext_vector_type(4))) float f32x4;

constexpr float LN_EPS = 1e-6f;
constexpr float NEG_INF = -3.402823466e38f;
constexpr float INV_SQRT_D = 0.17677669529663687f;  // 1/sqrt(32)

// round-to-nearest-even f32 -> bf16
static __device__ __forceinline__ unsigned short f2bf(float f) {
  unsigned u = __float_as_uint(f);
  u = u + 0x7fffu + ((u >> 16) & 1u);
  return (unsigned short)(u >> 16);
}
static __device__ __forceinline__ float bf2f(unsigned short s) {
  return __uint_as_float(((unsigned)s) << 16);
}

// async global->LDS, 16B per lane
static __device__ __forceinline__ void gload16(const void* gsrc, void* ldst) {
  __builtin_amdgcn_global_load_lds(
      (const __attribute__((address_space(1))) unsigned int*)gsrc,
      (__attribute__((address_space(3))) unsigned int*)ldst, 16, 0, 0);
}

// ---------------------------------------------------------------------------
// K0: weight prep.
//  idx < 65536: Wc2 = [W_K;W_V] bf16 MFMA-fragment-linear (verified layout):
//    ((kk*16+n)*64+lane)*8+j = Wc[n*16+(lane&15)][kk*32+(lane>>4)*8+j]
//  else       : Wq2 = W_Q frag-linear, N=128 (8 n-frags), K=128 (4 kk)
// ---------------------------------------------------------------------------
__global__ void conv_weights_kernel(const float* __restrict__ W_K,
                                    const float* __restrict__ W_V,
                                    const float* __restrict__ W_Q,
                                    unsigned short* __restrict__ Wc2,
                                    unsigned short* __restrict__ Wq2)
{
  int idx = blockIdx.x * 256 + threadIdx.x;   // 0..81919
  if (idx < 65536) {
    int e = idx >> 3, j = idx & 7;
    int kk = e >> 10, n = (e >> 6) & 15, lane = e & 63;
    int r = n*16 + (lane & 15);
    int c = kk*32 + (lane >> 4)*8 + j;
    float v = (r < TH) ? W_K[(size_t)r*TNIN + c] : W_V[(size_t)(r-TH)*TNIN + c];
    Wc2[idx] = f2bf(v);
  } else {
    int i2 = idx - 65536;                     // 0..16383
    int e = i2 >> 3, j = i2 & 7;
    int kk = e >> 9, n = (e >> 6) & 7, lane = e & 63;
    int r = n*16 + (lane & 15);
    int c = kk*32 + (lane >> 4)*8 + j;
    Wq2[i2] = f2bf(W_Q[(size_t)r*TH + c]);
  }
}

// ---------------------------------------------------------------------------
// K1a: KV = A @ Wc^T   (A = h_e flat [240000 x 256] f32, KV bf16 [240000 x 256])
// grid 1875 x 512 thr (8 waves, 2M x 4N). M-tile 128, K in 8 steps of 32.
// B (Wc2) triple-buffered gload_lds dist-2; A global->reg->bf16->ds_write dist-1.
// Swapped-operand MFMA: acc = mfma(b, a) => lane holds 4 consecutive C-cols.
// ---------------------------------------------------------------------------
__global__ __launch_bounds__(512, 4) void kv_gemm_kernel(
    const float* __restrict__ A, const unsigned short* __restrict__ Wc2,
    unsigned short* __restrict__ KVg)
{
  const int m0   = blockIdx.x * 128;
  const int tid  = threadIdx.x;
  const int wave = tid >> 6;
  const int lane = tid & 63;
  const int lm   = lane & 15;
  const int lgp  = lane >> 4;
  const int mh   = wave >> 2;   // 0..1
  const int nq   = wave & 3;    // 0..3

  __shared__ __align__(16) char smem[69632];
  unsigned short* Bl = (unsigned short*)smem;        // [3][8192]
  unsigned short* Al = (unsigned short*)(smem + 49152); // [2][128][40]
  unsigned short* Ct = (unsigned short*)smem;        // [128][264] overlay

  const int rowa = tid >> 2, cga = tid & 3;
  const float* aptr = A + (size_t)(m0 + rowa)*TNIN + cga*8;

  #define ISSUE_B(K)                                                             \
    { gload16(Wc2 + (size_t)(K)*8192 + tid*8,       &Bl[((K)%3)*8192 + tid*8]);  \
      gload16(Wc2 + (size_t)(K)*8192 + (tid+512)*8, &Bl[((K)%3)*8192 + (tid+512)*8]); }

  #define WRITE_A(K, S)                                                     \
    { short8v w;                                                            \
      w[0]=(short)f2bf(ra[S][0].x); w[1]=(short)f2bf(ra[S][0].y);           \
      w[2]=(short)f2bf(ra[S][0].z); w[3]=(short)f2bf(ra[S][0].w);           \
      w[4]=(short)f2bf(ra[S][1].x); w[5]=(short)f2bf(ra[S][1].y);           \
      w[6]=(short)f2bf(ra[S][1].z); w[7]=(short)f2bf(ra[S][1].w);           \
      *(short8v*)&Al[(((K)&1)*128 + rowa)*40 + cga*8] = w; }

  float4 ra[2][2];
  f32x4 acc[4][4] = {};

  // prologue: rA(0); B(0); B(1); rA(1); write A(0)
  ra[0][0] = *(const float4*)(aptr + 0);
  ra[0][1] = *(const float4*)(aptr + 4);
  ISSUE_B(0);
  ISSUE_B(1);
  ra[1][0] = *(const float4*)(aptr + 32);
  ra[1][1] = *(const float4*)(aptr + 36);
  WRITE_A(0, 0);

  #pragma unroll
  for (int k = 0; k < 8; ++k) {
    if (k == 7) asm volatile("s_waitcnt vmcnt(0)" ::: "memory");
    else        asm volatile("s_waitcnt vmcnt(4)" ::: "memory");
    __builtin_amdgcn_s_barrier();

    if (k < 6) {
      ISSUE_B(k+2);
      ra[k&1][0] = *(const float4*)(aptr + (k+2)*32);
      ra[k&1][1] = *(const float4*)(aptr + (k+2)*32 + 4);
    }

    short8v af[4];
    #pragma unroll
    for (int m = 0; m < 4; ++m)
      af[m] = *(const short8v*)&Al[((k&1)*128 + mh*64 + m*16 + lm)*40 + lgp*8];

    #pragma unroll
    for (int n = 0; n < 4; ++n) {
      short8v b = *(const short8v*)&Bl[(k%3)*8192 + ((nq*4 + n)*64 + lane)*8];
      #pragma unroll
      for (int m = 0; m < 4; ++m)
        acc[m][n] = __builtin_amdgcn_mfma_f32_16x16x32_bf16(b, af[m], acc[m][n], 0, 0, 0);
    }

    if (k < 7) WRITE_A(k+1, (k+1)&1);
  }
  #undef ISSUE_B
  #undef WRITE_A

  __syncthreads();   // all Bl/Al reads done before Ct overlay

  // C^T lanes: row = mf*16+lm (KV row), cols nf*16 + lgp*4 .. +3 (consecutive)
  #pragma unroll
  for (int m = 0; m < 4; ++m) {
    int row = mh*64 + m*16 + lm;
    #pragma unroll
    for (int n = 0; n < 4; ++n) {
      int col = nq*64 + n*16 + lgp*4;
      short4v p;
      p[0]=(short)f2bf(acc[m][n][0]); p[1]=(short)f2bf(acc[m][n][1]);
      p[2]=(short)f2bf(acc[m][n][2]); p[3]=(short)f2bf(acc[m][n][3]);
      *(short4v*)&Ct[row*264 + col] = p;
    }
  }
  __syncthreads();

  // coalesced copy out: 512B per row, rows contiguous
  #pragma unroll
  for (int p = 0; p < 8; ++p) {
    int t = p*512 + tid;
    int row = t >> 5, cg = t & 31;
    *(short8v*)&KVg[(size_t)(m0 + row)*256 + cg*8] =
        *(const short8v*)&Ct[row*264 + cg*8];
  }
}

// ---------------------------------------------------------------------------
// K1b: Q = h_v @ W_Q^T  (M=8000, N=128, K=128) -> Qg bf16.
// grid 63 x 512 thr. Whole B (32KB) staged once; A dbuf over 4 k-steps.
// ---------------------------------------------------------------------------
__global__ __launch_bounds__(512, 4) void q_gemm_kernel(
    const float* __restrict__ h_v, const unsigned short* __restrict__ Wq2,
    unsigned short* __restrict__ Qg)
{
  const int m0   = blockIdx.x * 128;
  const int tid  = threadIdx.x;
  const int wave = tid >> 6;
  const int lane = tid & 63;
  const int lm   = lane & 15;
  const int lgp  = lane >> 4;
  const int mh   = wave >> 2;   // 0..1
  const int nq   = wave & 3;    // 0..3

  __shared__ __align__(16) char smem[53248];
  unsigned short* Bq = (unsigned short*)smem;           // [16384]
  unsigned short* Al = (unsigned short*)(smem + 32768); // [2][128][40]
  unsigned short* Ct = (unsigned short*)smem;           // [128][136] overlay

  const int rowa = tid >> 2, cga = tid & 3;
  int rc = m0 + rowa; if (rc > NTOK-1) rc = NTOK-1;
  const float* aptr = h_v + (size_t)rc*TH + cga*8;

  #define WRITE_A(K, S)                                                     \
    { short8v w;                                                            \
      w[0]=(short)f2bf(ra[S][0].x); w[1]=(short)f2bf(ra[S][0].y);           \
      w[2]=(short)f2bf(ra[S][0].z); w[3]=(short)f2bf(ra[S][0].w);           \
      w[4]=(short)f2bf(ra[S][1].x); w[5]=(short)f2bf(ra[S][1].y);           \
      w[6]=(short)f2bf(ra[S][1].z); w[7]=(short)f2bf(ra[S][1].w);           \
      *(short8v*)&Al[(((K)&1)*128 + rowa)*40 + cga*8] = w; }

  float4 ra[2][2];
  f32x4 acc[4][2] = {};

  ra[0][0] = *(const float4*)(aptr + 0);
  ra[0][1] = *(const float4*)(aptr + 4);
  #pragma unroll
  for (int p = 0; p < 4; ++p)
    gload16(Wq2 + (size_t)(tid + p*512)*8, &Bq[(tid + p*512)*8]);
  ra[1][0] = *(const float4*)(aptr + 32);
  ra[1][1] = *(const float4*)(aptr + 36);
  WRITE_A(0, 0);

  #pragma unroll
  for (int k = 0; k < 4; ++k) {
    if (k == 0) asm volatile("s_waitcnt vmcnt(2)" ::: "memory");  // B done (ra1 may remain)
    __builtin_amdgcn_s_barrier();

    if (k < 2) {
      ra[k&1][0] = *(const float4*)(aptr + (k+2)*32);
      ra[k&1][1] = *(const float4*)(aptr + (k+2)*32 + 4);
    }

    short8v af[4];
    #pragma unroll
    for (int m = 0; m < 4; ++m)
      af[m] = *(const short8v*)&Al[((k&1)*128 + mh*64 + m*16 + lm)*40 + lgp*8];

    #pragma unroll
    for (int n = 0; n < 2; ++n) {
      short8v b = *(const short8v*)&Bq[((k*8 + nq*2 + n)*64 + lane)*8];
      #pragma unroll
      for (int m = 0; m < 4; ++m)
        acc[m][n] = __builtin_amdgcn_mfma_f32_16x16x32_bf16(b, af[m], acc[m][n], 0, 0, 0);
    }

    if (k < 3) WRITE_A(k+1, (k+1)&1);
  }
  #undef WRITE_A

  __syncthreads();
  #pragma unroll
  for (int m = 0; m < 4; ++m) {
    int row = mh*64 + m*16 + lm;
    #pragma unroll
    for (int n = 0; n < 2; ++n) {
      int col = nq*32 + n*16 + lgp*4;
      short4v p;
      p[0]=(short)f2bf(acc[m][n][0]); p[1]=(short)f2bf(acc[m][n][1]);
      p[2]=(short)f2bf(acc[m][n][2]); p[3]=(short)f2bf(acc[m][n][3]);
      *(short4v*)&Ct[row*136 + col] = p;
    }
  }
  __syncthreads();
  #pragma unroll
  for (int p = 0; p < 4; ++p) {
    int t = p*512 + tid;
    int row = t >> 4, cg = t & 15;
    if (m0 + row < NTOK)
      *(short8v*)&Qg[(size_t)(m0 + row)*TH + cg*8] =
          *(const short8v*)&Ct[row*136 + cg*8];
  }
}

// ---------------------------------------------------------------------------
// K2: attention core: logits -> masked softmax -> PV.  4 tokens/block x 512.
// Tiny LDS -> full occupancy; KV/Qg are L3-resident.
// ---------------------------------------------------------------------------
__global__ __launch_bounds__(512) void attn_core_kernel(
    const unsigned short* __restrict__ Qg, const unsigned short* __restrict__ KVg,
    const float* __restrict__ mask_attend, float* __restrict__ ul)
{
  const int tid  = threadIdx.x;
  const int tok  = tid >> 7;
  const int gtok = blockIdx.x * 4 + tok;
  __shared__ float att[4][4][32];

  {
    int h = (tid >> 5) & 3, k = tid & 31;
    float s = 0.f;
    float ma = 0.f;
    if (k < TK) {
      const unsigned short* qp = Qg  + (size_t)gtok*TH + h*32;
      const unsigned short* kp = KVg + ((size_t)gtok*TK + k)*TNIN + h*32;
      #pragma unroll
      for (int j = 0; j < 4; ++j) {
        short8v qf = *(const short8v*)(qp + j*8);
        short8v kf = *(const short8v*)(kp + j*8);
        #pragma unroll
        for (int e = 0; e < 8; ++e)
          s += bf2f((unsigned short)qf[e]) * bf2f((unsigned short)kf[e]);
      }
      ma = mask_attend[(size_t)gtok*TK + k];
    }
    bool ok = (k < TK) && (ma > 0.f);
    float val = ok ? s * INV_SQRT_D : NEG_INF;
    float mm = val;
    #pragma unroll
    for (int d = 16; d >= 1; d >>= 1) mm = fmaxf(mm, __shfl_xor(mm, d, 32));
    float e = ok ? expf(val - mm) : 0.f;
    float ss = e;
    #pragma unroll
    for (int d = 16; d >= 1; d >>= 1) ss += __shfl_xor(ss, d, 32);
    att[tok][h][k] = e / ss;
  }
  __syncthreads();
  {
    int c = tid & 127;
    const float* ar = att[tok][c >> 5];
    const unsigned short* vp = KVg + (size_t)gtok*TK*TNIN + TH + c;
    float u = 0.f;
    #pragma unroll
    for (int k = 0; k < TK; ++k)
      u += ar[k] * bf2f(vp[(size_t)k*TNIN]);
    ul[(size_t)gtok*TH + c] = u;
  }
}

// ---------------------------------------------------------------------------
// K2b: Hn = LN0(h_v + ul @ W_O^T)   (ffn1-style staging, ffn2-style epilogue)
// ---------------------------------------------------------------------------
__global__ __launch_bounds__(256) void wo_ln_kernel(
    const float* __restrict__ ul, const float* __restrict__ W_O,
    const float* __restrict__ h_v, const float* __restrict__ gain0,
    const float* __restrict__ bias0, float* __restrict__ Hn)
{
  const int tid  = threadIdx.x;
  const int tok0 = blockIdx.x * 32;
  __shared__ float Aa[32][128];
  __shared__ float Wt[128][128];

  for (int t = tid; t < 32*32; t += 256) {
    int row = t >> 5, i4 = t & 31;
    *(float4*)&Aa[row][i4*4] = *(const float4*)&ul[(size_t)(tok0+row)*TH + i4*4];
  }
  for (int t = tid; t < 128*32; t += 256) {
    int f = t & 127, i4 = t >> 7;
    float4 w = *(const float4*)&W_O[(size_t)f*TH + i4*4];
    Wt[i4*4+0][f]=w.x; Wt[i4*4+1][f]=w.y; Wt[i4*4+2][f]=w.z; Wt[i4*4+3][f]=w.w;
  }
  __syncthreads();

  const int tokg = tid>>5, colg = tid&31;
  float acc[4][4] = {};
  for (int i = 0; i < TH; i += 4){
    float a[4][4];
    #pragma unroll
    for (int r=0;r<4;r++){
      float4 tv=*(const float4*)&Aa[tokg*4+r][i];
      a[r][0]=tv.x;a[r][1]=tv.y;a[r][2]=tv.z;a[r][3]=tv.w;
    }
    #pragma unroll
    for (int d=0; d<4; ++d){
      float4 wv = *(const float4*)&Wt[i+d][colg*4];
      #pragma unroll
      for (int r=0;r<4;r++){
        acc[r][0]+=a[r][d]*wv.x; acc[r][1]+=a[r][d]*wv.y;
        acc[r][2]+=a[r][d]*wv.z; acc[r][3]+=a[r][d]*wv.w;
      }
    }
  }

  float4 g  = *(const float4*)&gain0[colg*4];
  float4 bb = *(const float4*)&bias0[colg*4];
  #pragma unroll
  for (int r=0;r<4;r++){
    int tok = tok0 + tokg*4 + r;
    float4 hv = *(const float4*)&h_v[(size_t)tok*TH + colg*4];
    float x0 = acc[r][0]+hv.x;
    float x1 = acc[r][1]+hv.y;
    float x2 = acc[r][2]+hv.z;
    float x3 = acc[r][3]+hv.w;
    float s1 = x0+x1+x2+x3;
    float s2 = x0*x0+x1*x1+x2*x2+x3*x3;
    #pragma unroll
    for (int m=16;m>=1;m>>=1){ s1 += __shfl_xor(s1,m,32); s2 += __shfl_xor(s2,m,32); }
    float mu  = s1*(1.f/128.f);
    float var = (s2 - 128.f*mu*mu)*(1.f/127.f);
    float inv = 1.f/(sqrtf(var+LN_EPS)+LN_EPS);
    float4 y;
    y.x = g.x*(x0-mu)*inv + bb.x;
    y.y = g.y*(x1-mu)*inv + bb.y;
    y.z = g.z*(x2-mu)*inv + bb.z;
    y.w = g.w*(x3-mu)*inv + bb.w;
    *(float4*)&Hn[(size_t)tok*TH + colg*4] = y;
  }
}

// ---------------------------------------------------------------------------
// K3: Z = relu(Hn @ W_in^T + b_in)   (unchanged, verified)
// ---------------------------------------------------------------------------
__global__ __launch_bounds__(256) void ffn1_kernel(
    const float* __restrict__ Hn, const float* __restrict__ W_in,
    const float* __restrict__ b_in, float* __restrict__ Z)
{
  const int tid  = threadIdx.x;
  const int tok0 = blockIdx.x * 32;
  const int f0   = blockIdx.y * 128;
  __shared__ float A[32][128];
  __shared__ float Wt[128][128];

  for (int t = tid; t < 32*32; t += 256) {
    int row = t >> 5, i4 = t & 31;
    *(float4*)&A[row][i4*4] = *(const float4*)&Hn[(size_t)(tok0+row)*TH + i4*4];
  }
  for (int t = tid; t < 128*32; t += 256) {
    int f = t & 127, i4 = t >> 7;
    float4 w = *(const float4*)&W_in[(size_t)(f0+f)*TH + i4*4];
    Wt[i4*4+0][f]=w.x; Wt[i4*4+1][f]=w.y; Wt[i4*4+2][f]=w.z; Wt[i4*4+3][f]=w.w;
  }
  __syncthreads();

  const int tokg = tid>>5, colg = tid&31;
  float acc[4][4] = {};
  for (int i = 0; i < TH; i += 4){
    float a[4][4];
    #pragma unroll
    for (int r=0;r<4;r++){
      float4 tv=*(const float4*)&A[tokg*4+r][i];
      a[r][0]=tv.x;a[r][1]=tv.y;a[r][2]=tv.z;a[r][3]=tv.w;
    }
    #pragma unroll
    for (int d=0; d<4; ++d){
      float4 wv = *(const float4*)&Wt[i+d][colg*4];
      #pragma unroll
      for (int r=0;r<4;r++){
        acc[r][0]+=a[r][d]*wv.x; acc[r][1]+=a[r][d]*wv.y;
        acc[r][2]+=a[r][d]*wv.z; acc[r][3]+=a[r][d]*wv.w;
      }
    }
  }
  float4 bv = *(const float4*)&b_in[f0 + colg*4];
  #pragma unroll
  for (int r=0;r<4;r++){
    float4 z;
    z.x = fmaxf(acc[r][0]+bv.x, 0.f);
    z.y = fmaxf(acc[r][1]+bv.y, 0.f);
    z.z = fmaxf(acc[r][2]+bv.z, 0.f);
    z.w = fmaxf(acc[r][3]+bv.w, 0.f);
    *(float4*)&Z[(size_t)(tok0+tokg*4+r)*TDFF + f0 + colg*4] = z;
  }
}

// ---------------------------------------------------------------------------
// K4: out = mask_v * LN1(Hn + Z @ W_out^T + b_out)   (unchanged, verified)
// ---------------------------------------------------------------------------
__global__ __launch_bounds__(256) void ffn2_kernel(
    const float* __restrict__ Z, const float* __restrict__ W_out,
    const float* __restrict__ b_out, const float* __restrict__ Hn,
    const float* __restrict__ gain1, const float* __restrict__ bias1,
    const float* __restrict__ mask_v, float* __restrict__ out)
{
  const int tid  = threadIdx.x;
  const int tok0 = blockIdx.x * 32;
  __shared__ float A[32][128];
  __shared__ float Wt[128][128];

  const int tokg = tid>>5, colg = tid&31;
  float acc[4][4] = {};

  for (int c = 0; c < 4; ++c){
    __syncthreads();
    for (int t = tid; t < 32*32; t += 256){
      int row = t>>5, i4 = t&31;
      *(float4*)&A[row][i4*4] = *(const float4*)&Z[(size_t)(tok0+row)*TDFF + c*128 + i4*4];
    }
    for (int t = tid; t < 128*32; t += 256){
      int j = t & 127, i4 = t >> 7;
      float4 w = *(const float4*)&W_out[(size_t)j*TDFF + c*128 + i4*4];
      Wt[i4*4+0][j]=w.x; Wt[i4*4+1][j]=w.y; Wt[i4*4+2][j]=w.z; Wt[i4*4+3][j]=w.w;
    }
    __syncthreads();
    for (int i = 0; i < 128; i += 4){
      float a[4][4];
      #pragma unroll
      for (int r=0;r<4;r++){
        float4 tv=*(const float4*)&A[tokg*4+r][i];
        a[r][0]=tv.x;a[r][1]=tv.y;a[r][2]=tv.z;a[r][3]=tv.w;
      }
      #pragma unroll
      for (int d=0; d<4; ++d){
        float4 wv = *(const float4*)&Wt[i+d][colg*4];
        #pragma unroll
        for (int r=0;r<4;r++){
          acc[r][0]+=a[r][d]*wv.x; acc[r][1]+=a[r][d]*wv.y;
          acc[r][2]+=a[r][d]*wv.z; acc[r][3]+=a[r][d]*wv.w;
        }
      }
    }
  }

  float4 bo = *(const float4*)&b_out[colg*4];
  float4 g  = *(const float4*)&gain1[colg*4];
  float4 bb = *(const float4*)&bias1[colg*4];
  #pragma unroll
  for (int r=0;r<4;r++){
    int tok = tok0 + tokg*4 + r;
    float4 hn = *(const float4*)&Hn[(size_t)tok*TH + colg*4];
    float x0 = acc[r][0]+bo.x+hn.x;
    float x1 = acc[r][1]+bo.y+hn.y;
    float x2 = acc[r][2]+bo.z+hn.z;
    float x3 = acc[r][3]+bo.w+hn.w;
    float s1 = x0+x1+x2+x3;
    float s2 = x0*x0+x1*x1+x2*x2+x3*x3;
    #pragma unroll
    for (int m=16;m>=1;m>>=1){ s1 += __shfl_xor(s1,m,32); s2 += __shfl_xor(s2,m,32); }
    float mu  = s1*(1.f/128.f);
    float var = (s2 - 128.f*mu*mu)*(1.f/127.f);
    float inv = 1.f/(sqrtf(var+LN_EPS)+LN_EPS);
    float mv  = mask_v[tok];
    float4 y;
    y.x = mv*(g.x*(x0-mu)*inv + bb.x);
    y.y = mv*(g.y*(x1-mu)*inv + bb.y);
    y.z = mv*(g.z*(x2-mu)*inv + bb.z);
    y.w = mv*(g.w*(x3-mu)*inv + bb.w);
    *(float4*)&out[(size_t)tok*TH + colg*4] = y;
  }
}

// ---------------------------------------------------------------------------
extern "C" void kernel_launch(void* const* d_in, const int* in_sizes, int n_in,
                              void* d_out, int out_size, void* d_ws, size_t ws_size,
                              hipStream_t stream)
{
  const float* h_v         = (const float*)d_in[0];
  const float* h_e         = (const float*)d_in[1];
  const float* mask_v      = (const float*)d_in[2];
  const float* mask_attend = (const float*)d_in[3];
  const float* W_Q   = (const float*)d_in[4];
  const float* W_K   = (const float*)d_in[5];
  const float* W_V   = (const float*)d_in[6];
  const float* W_O   = (const float*)d_in[7];
  const float* gain0 = (const float*)d_in[8];
  const float* bias0 = (const float*)d_in[9];
  const float* gain1 = (const float*)d_in[10];
  const float* bias1 = (const float*)d_in[11];
  const float* W_in  = (const float*)d_in[12];
  const float* b_in  = (const float*)d_in[13];
  const float* W_out = (const float*)d_in[14];
  const float* b_out = (const float*)d_in[15];

  float* out = (float*)d_out;
  char* ws = (char*)d_ws;
  unsigned short* KVg = (unsigned short*)ws;                 // 122,880,000 B
  unsigned short* Qg  = (unsigned short*)(ws + 122880000);   //   2,048,000 B
  unsigned short* Wc2 = (unsigned short*)(ws + 124928000);   //     131,072 B
  unsigned short* Wq2 = (unsigned short*)(ws + 125059072);   //      32,768 B
  float* ul = (float*)(ws + 125091840);                      //   4,096,000 B
  float* Hn = (float*)(ws + 129187840);                      //   4,096,000 B
  float* Z  = (float*)(ws + 133283840);                      //  16,384,000 B

  conv_weights_kernel<<<320, 256, 0, stream>>>(W_K, W_V, W_Q, Wc2, Wq2);
  kv_gemm_kernel<<<MROWS/128, 512, 0, stream>>>(h_e, Wc2, KVg);
  q_gemm_kernel<<<(NTOK + 127)/128, 512, 0, stream>>>(h_v, Wq2, Qg);
  attn_core_kernel<<<NTOK/4, 512, 0, stream>>>(Qg, KVg, mask_attend, ul);
  wo_ln_kernel<<<NTOK/32, 256, 0, stream>>>(ul, W_O, h_v, gain0, bias0, Hn);
  ffn1_kernel<<<dim3(NTOK/32, TDFF/128), 256, 0, stream>>>(Hn, W_in, b_in, Z);
  ffn2_kernel<<<NTOK/32, 256, 0, stream>>>(Z, W_out, b_out, Hn, gain1, bias1,
                                           mask_v, out);
}

// Round 7
// 145.814 us; speedup vs baseline: 1.2855x; 1.2855x over previous
//
#include <hip/hip_runtime.h>
#include <math.h>

#define TK 30
#define TH 128
#define TNIN 256
#define TDFF 512
#define NTOK 8000
#define ROWP 264   // KVs row stride in u16 (528B: 16B-aligned, 4-way worst bank)

typedef __attribute__((ext_vector_type(8))) short short8v;
typedef __attribute__((ext_vector_type(4))) short short4v;
typedef __attribute__((ext_vector_type(4))) float f32x4;

constexpr float LN_EPS = 1e-6f;
constexpr float NEG_INF = -3.402823466e38f;
constexpr float INV_SQRT_D = 0.17677669529663687f;  // 1/sqrt(32)

// round-to-nearest-even f32 -> bf16
static __device__ __forceinline__ unsigned short f2bf(float f) {
  unsigned u = __float_as_uint(f);
  u = u + 0x7fffu + ((u >> 16) & 1u);
  return (unsigned short)(u >> 16);
}
static __device__ __forceinline__ float bf2f(unsigned short s) {
  return __uint_as_float(((unsigned)s) << 16);
}

// async global->LDS, 16B per lane
static __device__ __forceinline__ void gload16(const void* gsrc, void* ldst) {
  __builtin_amdgcn_global_load_lds(
      (const __attribute__((address_space(1))) unsigned int*)gsrc,
      (__attribute__((address_space(3))) unsigned int*)ldst, 16, 0, 0);
}

// ---------------------------------------------------------------------------
// K0: weight prep (verbatim R6, verified).
//  idx < 65536: Wc2 = [W_K;W_V] bf16 MFMA-fragment-linear
//  else       : Wq2 = W_Q frag-linear, N=128, K=128
// ---------------------------------------------------------------------------
__global__ void conv_weights_kernel(const float* __restrict__ W_K,
                                    const float* __restrict__ W_V,
                                    const float* __restrict__ W_Q,
                                    unsigned short* __restrict__ Wc2,
                                    unsigned short* __restrict__ Wq2)
{
  int idx = blockIdx.x * 256 + threadIdx.x;   // 0..81919
  if (idx < 65536) {
    int e = idx >> 3, j = idx & 7;
    int kk = e >> 10, n = (e >> 6) & 15, lane = e & 63;
    int r = n*16 + (lane & 15);
    int c = kk*32 + (lane >> 4)*8 + j;
    float v = (r < TH) ? W_K[(size_t)r*TNIN + c] : W_V[(size_t)(r-TH)*TNIN + c];
    Wc2[idx] = f2bf(v);
  } else {
    int i2 = idx - 65536;                     // 0..16383
    int e = i2 >> 3, j = i2 & 7;
    int kk = e >> 9, n = (e >> 6) & 7, lane = e & 63;
    int r = n*16 + (lane & 15);
    int c = kk*32 + (lane >> 4)*8 + j;
    Wq2[i2] = f2bf(W_Q[(size_t)r*TH + c]);
  }
}

// ---------------------------------------------------------------------------
// K1: fused KV-GEMM (R6 core, verified) + attention core.
// grid = 2000 x 512 thr. M-tile = 128 rows = 4 tokens (120 real + 8 clamped).
// GEMM result -> KVs[128][264] bf16 LDS overlay; tail: logits/softmax, PV.
// LDS 69.6 KB -> 2 blocks/CU.
// ---------------------------------------------------------------------------
__global__ __launch_bounds__(512, 4) void kvattn_kernel(
    const float* __restrict__ A, const unsigned short* __restrict__ Wc2,
    const unsigned short* __restrict__ Qg, const float* __restrict__ mask_attend,
    float* __restrict__ ul)
{
  const int tid  = threadIdx.x;
  const int wave = tid >> 6;
  const int lane = tid & 63;
  const int lm   = lane & 15;
  const int lgp  = lane >> 4;
  const int mh   = wave >> 2;   // 0..1
  const int nq   = wave & 3;    // 0..3

  __shared__ __align__(16) char smem[69632];
  unsigned short* Bl  = (unsigned short*)smem;          // [3][8192]
  unsigned short* Al  = (unsigned short*)(smem + 49152);// [2][128][40]
  unsigned short* KVs = (unsigned short*)smem;          // [128][264] overlay
  float* att = (float*)(smem + 67584);                  // [4][4][32]

  // ---- A addressing: block rows = blockIdx.x*120 + rowa (clamped) ----
  const int rowa = tid >> 2, cga = tid & 3;
  const int rowc = (rowa > 119) ? 119 : rowa;
  const float* aptr = A + ((size_t)blockIdx.x*120 + rowc)*TNIN + cga*8;

  #define ISSUE_B(K)                                                             \
    { gload16(Wc2 + (size_t)(K)*8192 + tid*8,       &Bl[((K)%3)*8192 + tid*8]);  \
      gload16(Wc2 + (size_t)(K)*8192 + (tid+512)*8, &Bl[((K)%3)*8192 + (tid+512)*8]); }

  #define WRITE_A(K, S)                                                     \
    { short8v w;                                                            \
      w[0]=(short)f2bf(ra[S][0].x); w[1]=(short)f2bf(ra[S][0].y);           \
      w[2]=(short)f2bf(ra[S][0].z); w[3]=(short)f2bf(ra[S][0].w);           \
      w[4]=(short)f2bf(ra[S][1].x); w[5]=(short)f2bf(ra[S][1].y);           \
      w[6]=(short)f2bf(ra[S][1].z); w[7]=(short)f2bf(ra[S][1].w);           \
      *(short8v*)&Al[(((K)&1)*128 + rowa)*40 + cga*8] = w; }

  float4 ra[2][2];
  f32x4 acc[4][4] = {};

  // prologue: rA(0); B(0); B(1); rA(1); write A(0)
  ra[0][0] = *(const float4*)(aptr + 0);
  ra[0][1] = *(const float4*)(aptr + 4);
  ISSUE_B(0);
  ISSUE_B(1);
  ra[1][0] = *(const float4*)(aptr + 32);
  ra[1][1] = *(const float4*)(aptr + 36);
  WRITE_A(0, 0);

  #pragma unroll
  for (int k = 0; k < 8; ++k) {
    if (k == 7) asm volatile("s_waitcnt vmcnt(0)" ::: "memory");
    else        asm volatile("s_waitcnt vmcnt(4)" ::: "memory");
    __builtin_amdgcn_s_barrier();

    if (k < 6) {
      ISSUE_B(k+2);
      ra[k&1][0] = *(const float4*)(aptr + (k+2)*32);
      ra[k&1][1] = *(const float4*)(aptr + (k+2)*32 + 4);
    }

    short8v af[4];
    #pragma unroll
    for (int m = 0; m < 4; ++m)
      af[m] = *(const short8v*)&Al[((k&1)*128 + mh*64 + m*16 + lm)*40 + lgp*8];

    #pragma unroll
    for (int n = 0; n < 4; ++n) {
      short8v b = *(const short8v*)&Bl[(k%3)*8192 + ((nq*4 + n)*64 + lane)*8];
      #pragma unroll
      for (int m = 0; m < 4; ++m)
        acc[m][n] = __builtin_amdgcn_mfma_f32_16x16x32_bf16(b, af[m], acc[m][n], 0, 0, 0);
    }

    if (k < 7) WRITE_A(k+1, (k+1)&1);
  }
  #undef ISSUE_B
  #undef WRITE_A

  __syncthreads();   // all Bl/Al reads done before KVs overlay

  // C^T writeout (verified swapped-operand mapping):
  // row = mh*64+m*16+lm (KV row), cols nq*64+n*16+lgp*4 .. +3
  #pragma unroll
  for (int m = 0; m < 4; ++m) {
    int row = mh*64 + m*16 + lm;
    #pragma unroll
    for (int n = 0; n < 4; ++n) {
      int col = nq*64 + n*16 + lgp*4;
      short4v p;
      p[0]=(short)f2bf(acc[m][n][0]); p[1]=(short)f2bf(acc[m][n][1]);
      p[2]=(short)f2bf(acc[m][n][2]); p[3]=(short)f2bf(acc[m][n][3]);
      *(short4v*)&KVs[row*ROWP + col] = p;
    }
  }
  __syncthreads();

  // ---- logits + masked softmax (thread = (tok,h,k); 32-lane shfl) ----
  {
    int tok = tid >> 7, h = (tid >> 5) & 3, k = tid & 31;
    int gtok = blockIdx.x*4 + tok;
    float s = 0.f;
    float ma = 0.f;
    if (k < TK) {
      const unsigned short* qp = Qg + (size_t)gtok*TH + h*32;
      const unsigned short* kp = &KVs[(tok*TK + k)*ROWP + h*32];
      #pragma unroll
      for (int j = 0; j < 4; ++j) {
        short8v qf = *(const short8v*)(qp + j*8);
        short8v kf = *(const short8v*)(kp + j*8);
        #pragma unroll
        for (int e = 0; e < 8; ++e)
          s += bf2f((unsigned short)qf[e]) * bf2f((unsigned short)kf[e]);
      }
      ma = mask_attend[(size_t)gtok*TK + k];
    }
    bool ok = (k < TK) && (ma > 0.f);
    float val = ok ? s * INV_SQRT_D : NEG_INF;
    float mm = val;
    #pragma unroll
    for (int d = 16; d >= 1; d >>= 1) mm = fmaxf(mm, __shfl_xor(mm, d, 32));
    float e = ok ? expf(val - mm) : 0.f;
    float ss = e;
    #pragma unroll
    for (int d = 16; d >= 1; d >>= 1) ss += __shfl_xor(ss, d, 32);
    att[(tok*4 + h)*32 + k] = e / ss;
  }
  __syncthreads();

  // ---- PV: u = att @ Vp (thread = (tok,c); 2-lanes/bank row reads) ----
  {
    int tok = tid >> 7, c = tid & 127;
    int gtok = blockIdx.x*4 + tok;
    const float* ar = &att[(tok*4 + (c >> 5))*32];
    const unsigned short* vb = &KVs[tok*TK*ROWP + TH + c];
    float u = 0.f;
    #pragma unroll
    for (int k = 0; k < TK; ++k)
      u += ar[k] * bf2f(vb[k*ROWP]);
    ul[(size_t)gtok*TH + c] = u;
  }
}

// ---------------------------------------------------------------------------
// K1b: Q = h_v @ W_Q^T  (verbatim R6, verified)
// ---------------------------------------------------------------------------
__global__ __launch_bounds__(512, 4) void q_gemm_kernel(
    const float* __restrict__ h_v, const unsigned short* __restrict__ Wq2,
    unsigned short* __restrict__ Qg)
{
  const int m0   = blockIdx.x * 128;
  const int tid  = threadIdx.x;
  const int wave = tid >> 6;
  const int lane = tid & 63;
  const int lm   = lane & 15;
  const int lgp  = lane >> 4;
  const int mh   = wave >> 2;
  const int nq   = wave & 3;

  __shared__ __align__(16) char smem[53248];
  unsigned short* Bq = (unsigned short*)smem;           // [16384]
  unsigned short* Al = (unsigned short*)(smem + 32768); // [2][128][40]
  unsigned short* Ct = (unsigned short*)smem;           // [128][136] overlay

  const int rowa = tid >> 2, cga = tid & 3;
  int rc = m0 + rowa; if (rc > NTOK-1) rc = NTOK-1;
  const float* aptr = h_v + (size_t)rc*TH + cga*8;

  #define WRITE_A(K, S)                                                     \
    { short8v w;                                                            \
      w[0]=(short)f2bf(ra[S][0].x); w[1]=(short)f2bf(ra[S][0].y);           \
      w[2]=(short)f2bf(ra[S][0].z); w[3]=(short)f2bf(ra[S][0].w);           \
      w[4]=(short)f2bf(ra[S][1].x); w[5]=(short)f2bf(ra[S][1].y);           \
      w[6]=(short)f2bf(ra[S][1].z); w[7]=(short)f2bf(ra[S][1].w);           \
      *(short8v*)&Al[(((K)&1)*128 + rowa)*40 + cga*8] = w; }

  float4 ra[2][2];
  f32x4 acc[4][2] = {};

  ra[0][0] = *(const float4*)(aptr + 0);
  ra[0][1] = *(const float4*)(aptr + 4);
  #pragma unroll
  for (int p = 0; p < 4; ++p)
    gload16(Wq2 + (size_t)(tid + p*512)*8, &Bq[(tid + p*512)*8]);
  ra[1][0] = *(const float4*)(aptr + 32);
  ra[1][1] = *(const float4*)(aptr + 36);
  WRITE_A(0, 0);

  #pragma unroll
  for (int k = 0; k < 4; ++k) {
    if (k == 0) asm volatile("s_waitcnt vmcnt(2)" ::: "memory");
    __builtin_amdgcn_s_barrier();

    if (k < 2) {
      ra[k&1][0] = *(const float4*)(aptr + (k+2)*32);
      ra[k&1][1] = *(const float4*)(aptr + (k+2)*32 + 4);
    }

    short8v af[4];
    #pragma unroll
    for (int m = 0; m < 4; ++m)
      af[m] = *(const short8v*)&Al[((k&1)*128 + mh*64 + m*16 + lm)*40 + lgp*8];

    #pragma unroll
    for (int n = 0; n < 2; ++n) {
      short8v b = *(const short8v*)&Bq[((k*8 + nq*2 + n)*64 + lane)*8];
      #pragma unroll
      for (int m = 0; m < 4; ++m)
        acc[m][n] = __builtin_amdgcn_mfma_f32_16x16x32_bf16(b, af[m], acc[m][n], 0, 0, 0);
    }

    if (k < 3) WRITE_A(k+1, (k+1)&1);
  }
  #undef WRITE_A

  __syncthreads();
  #pragma unroll
  for (int m = 0; m < 4; ++m) {
    int row = mh*64 + m*16 + lm;
    #pragma unroll
    for (int n = 0; n < 2; ++n) {
      int col = nq*32 + n*16 + lgp*4;
      short4v p;
      p[0]=(short)f2bf(acc[m][n][0]); p[1]=(short)f2bf(acc[m][n][1]);
      p[2]=(short)f2bf(acc[m][n][2]); p[3]=(short)f2bf(acc[m][n][3]);
      *(short4v*)&Ct[row*136 + col] = p;
    }
  }
  __syncthreads();
  #pragma unroll
  for (int p = 0; p < 4; ++p) {
    int t = p*512 + tid;
    int row = t >> 4, cg = t & 15;
    if (m0 + row < NTOK)
      *(short8v*)&Qg[(size_t)(m0 + row)*TH + cg*8] =
          *(const short8v*)&Ct[row*136 + cg*8];
  }
}

// ---------------------------------------------------------------------------
// K2b: Hn = LN0(h_v + ul @ W_O^T)   (verbatim R6, verified)
// ---------------------------------------------------------------------------
__global__ __launch_bounds__(256) void wo_ln_kernel(
    const float* __restrict__ ul, const float* __restrict__ W_O,
    const float* __restrict__ h_v, const float* __restrict__ gain0,
    const float* __restrict__ bias0, float* __restrict__ Hn)
{
  const int tid  = threadIdx.x;
  const int tok0 = blockIdx.x * 32;
  __shared__ float Aa[32][128];
  __shared__ float Wt[128][128];

  for (int t = tid; t < 32*32; t += 256) {
    int row = t >> 5, i4 = t & 31;
    *(float4*)&Aa[row][i4*4] = *(const float4*)&ul[(size_t)(tok0+row)*TH + i4*4];
  }
  for (int t = tid; t < 128*32; t += 256) {
    int f = t & 127, i4 = t >> 7;
    float4 w = *(const float4*)&W_O[(size_t)f*TH + i4*4];
    Wt[i4*4+0][f]=w.x; Wt[i4*4+1][f]=w.y; Wt[i4*4+2][f]=w.z; Wt[i4*4+3][f]=w.w;
  }
  __syncthreads();

  const int tokg = tid>>5, colg = tid&31;
  float acc[4][4] = {};
  for (int i = 0; i < TH; i += 4){
    float a[4][4];
    #pragma unroll
    for (int r=0;r<4;r++){
      float4 tv=*(const float4*)&Aa[tokg*4+r][i];
      a[r][0]=tv.x;a[r][1]=tv.y;a[r][2]=tv.z;a[r][3]=tv.w;
    }
    #pragma unroll
    for (int d=0; d<4; ++d){
      float4 wv = *(const float4*)&Wt[i+d][colg*4];
      #pragma unroll
      for (int r=0;r<4;r++){
        acc[r][0]+=a[r][d]*wv.x; acc[r][1]+=a[r][d]*wv.y;
        acc[r][2]+=a[r][d]*wv.z; acc[r][3]+=a[r][d]*wv.w;
      }
    }
  }

  float4 g  = *(const float4*)&gain0[colg*4];
  float4 bb = *(const float4*)&bias0[colg*4];
  #pragma unroll
  for (int r=0;r<4;r++){
    int tok = tok0 + tokg*4 + r;
    float4 hv = *(const float4*)&h_v[(size_t)tok*TH + colg*4];
    float x0 = acc[r][0]+hv.x;
    float x1 = acc[r][1]+hv.y;
    float x2 = acc[r][2]+hv.z;
    float x3 = acc[r][3]+hv.w;
    float s1 = x0+x1+x2+x3;
    float s2 = x0*x0+x1*x1+x2*x2+x3*x3;
    #pragma unroll
    for (int m=16;m>=1;m>>=1){ s1 += __shfl_xor(s1,m,32); s2 += __shfl_xor(s2,m,32); }
    float mu  = s1*(1.f/128.f);
    float var = (s2 - 128.f*mu*mu)*(1.f/127.f);
    float inv = 1.f/(sqrtf(var+LN_EPS)+LN_EPS);
    float4 y;
    y.x = g.x*(x0-mu)*inv + bb.x;
    y.y = g.y*(x1-mu)*inv + bb.y;
    y.z = g.z*(x2-mu)*inv + bb.z;
    y.w = g.w*(x3-mu)*inv + bb.w;
    *(float4*)&Hn[(size_t)tok*TH + colg*4] = y;
  }
}

// ---------------------------------------------------------------------------
// K3: Z = relu(Hn @ W_in^T + b_in)   (unchanged, verified)
// ---------------------------------------------------------------------------
__global__ __launch_bounds__(256) void ffn1_kernel(
    const float* __restrict__ Hn, const float* __restrict__ W_in,
    const float* __restrict__ b_in, float* __restrict__ Z)
{
  const int tid  = threadIdx.x;
  const int tok0 = blockIdx.x * 32;
  const int f0   = blockIdx.y * 128;
  __shared__ float A[32][128];
  __shared__ float Wt[128][128];

  for (int t = tid; t < 32*32; t += 256) {
    int row = t >> 5, i4 = t & 31;
    *(float4*)&A[row][i4*4] = *(const float4*)&Hn[(size_t)(tok0+row)*TH + i4*4];
  }
  for (int t = tid; t < 128*32; t += 256) {
    int f = t & 127, i4 = t >> 7;
    float4 w = *(const float4*)&W_in[(size_t)(f0+f)*TH + i4*4];
    Wt[i4*4+0][f]=w.x; Wt[i4*4+1][f]=w.y; Wt[i4*4+2][f]=w.z; Wt[i4*4+3][f]=w.w;
  }
  __syncthreads();

  const int tokg = tid>>5, colg = tid&31;
  float acc[4][4] = {};
  for (int i = 0; i < TH; i += 4){
    float a[4][4];
    #pragma unroll
    for (int r=0;r<4;r++){
      float4 tv=*(const float4*)&A[tokg*4+r][i];
      a[r][0]=tv.x;a[r][1]=tv.y;a[r][2]=tv.z;a[r][3]=tv.w;
    }
    #pragma unroll
    for (int d=0; d<4; ++d){
      float4 wv = *(const float4*)&Wt[i+d][colg*4];
      #pragma unroll
      for (int r=0;r<4;r++){
        acc[r][0]+=a[r][d]*wv.x; acc[r][1]+=a[r][d]*wv.y;
        acc[r][2]+=a[r][d]*wv.z; acc[r][3]+=a[r][d]*wv.w;
      }
    }
  }
  float4 bv = *(const float4*)&b_in[f0 + colg*4];
  #pragma unroll
  for (int r=0;r<4;r++){
    float4 z;
    z.x = fmaxf(acc[r][0]+bv.x, 0.f);
    z.y = fmaxf(acc[r][1]+bv.y, 0.f);
    z.z = fmaxf(acc[r][2]+bv.z, 0.f);
    z.w = fmaxf(acc[r][3]+bv.w, 0.f);
    *(float4*)&Z[(size_t)(tok0+tokg*4+r)*TDFF + f0 + colg*4] = z;
  }
}

// ---------------------------------------------------------------------------
// K4: out = mask_v * LN1(Hn + Z @ W_out^T + b_out)   (unchanged, verified)
// ---------------------------------------------------------------------------
__global__ __launch_bounds__(256) void ffn2_kernel(
    const float* __restrict__ Z, const float* __restrict__ W_out,
    const float* __restrict__ b_out, const float* __restrict__ Hn,
    const float* __restrict__ gain1, const float* __restrict__ bias1,
    const float* __restrict__ mask_v, float* __restrict__ out)
{
  const int tid  = threadIdx.x;
  const int tok0 = blockIdx.x * 32;
  __shared__ float A[32][128];
  __shared__ float Wt[128][128];

  const int tokg = tid>>5, colg = tid&31;
  float acc[4][4] = {};

  for (int c = 0; c < 4; ++c){
    __syncthreads();
    for (int t = tid; t < 32*32; t += 256){
      int row = t>>5, i4 = t&31;
      *(float4*)&A[row][i4*4] = *(const float4*)&Z[(size_t)(tok0+row)*TDFF + c*128 + i4*4];
    }
    for (int t = tid; t < 128*32; t += 256){
      int j = t & 127, i4 = t >> 7;
      float4 w = *(const float4*)&W_out[(size_t)j*TDFF + c*128 + i4*4];
      Wt[i4*4+0][j]=w.x; Wt[i4*4+1][j]=w.y; Wt[i4*4+2][j]=w.z; Wt[i4*4+3][j]=w.w;
    }
    __syncthreads();
    for (int i = 0; i < 128; i += 4){
      float a[4][4];
      #pragma unroll
      for (int r=0;r<4;r++){
        float4 tv=*(const float4*)&A[tokg*4+r][i];
        a[r][0]=tv.x;a[r][1]=tv.y;a[r][2]=tv.z;a[r][3]=tv.w;
      }
      #pragma unroll
      for (int d=0; d<4; ++d){
        float4 wv = *(const float4*)&Wt[i+d][colg*4];
        #pragma unroll
        for (int r=0;r<4;r++){
          acc[r][0]+=a[r][d]*wv.x; acc[r][1]+=a[r][d]*wv.y;
          acc[r][2]+=a[r][d]*wv.z; acc[r][3]+=a[r][d]*wv.w;
        }
      }
    }
  }

  float4 bo = *(const float4*)&b_out[colg*4];
  float4 g  = *(const float4*)&gain1[colg*4];
  float4 bb = *(const float4*)&bias1[colg*4];
  #pragma unroll
  for (int r=0;r<4;r++){
    int tok = tok0 + tokg*4 + r;
    float4 hn = *(const float4*)&Hn[(size_t)tok*TH + colg*4];
    float x0 = acc[r][0]+bo.x+hn.x;
    float x1 = acc[r][1]+bo.y+hn.y;
    float x2 = acc[r][2]+bo.z+hn.z;
    float x3 = acc[r][3]+bo.w+hn.w;
    float s1 = x0+x1+x2+x3;
    float s2 = x0*x0+x1*x1+x2*x2+x3*x3;
    #pragma unroll
    for (int m=16;m>=1;m>>=1){ s1 += __shfl_xor(s1,m,32); s2 += __shfl_xor(s2,m,32); }
    float mu  = s1*(1.f/128.f);
    float var = (s2 - 128.f*mu*mu)*(1.f/127.f);
    float inv = 1.f/(sqrtf(var+LN_EPS)+LN_EPS);
    float mv  = mask_v[tok];
    float4 y;
    y.x = mv*(g.x*(x0-mu)*inv + bb.x);
    y.y = mv*(g.y*(x1-mu)*inv + bb.y);
    y.z = mv*(g.z*(x2-mu)*inv + bb.z);
    y.w = mv*(g.w*(x3-mu)*inv + bb.w);
    *(float4*)&out[(size_t)tok*TH + colg*4] = y;
  }
}

// ---------------------------------------------------------------------------
extern "C" void kernel_launch(void* const* d_in, const int* in_sizes, int n_in,
                              void* d_out, int out_size, void* d_ws, size_t ws_size,
                              hipStream_t stream)
{
  const float* h_v         = (const float*)d_in[0];
  const float* h_e         = (const float*)d_in[1];
  const float* mask_v      = (const float*)d_in[2];
  const float* mask_attend = (const float*)d_in[3];
  const float* W_Q   = (const float*)d_in[4];
  const float* W_K   = (const float*)d_in[5];
  const float* W_V   = (const float*)d_in[6];
  const float* W_O   = (const float*)d_in[7];
  const float* gain0 = (const float*)d_in[8];
  const float* bias0 = (const float*)d_in[9];
  const float* gain1 = (const float*)d_in[10];
  const float* bias1 = (const float*)d_in[11];
  const float* W_in  = (const float*)d_in[12];
  const float* b_in  = (const float*)d_in[13];
  const float* W_out = (const float*)d_in[14];
  const float* b_out = (const float*)d_in[15];

  float* out = (float*)d_out;
  char* ws = (char*)d_ws;
  unsigned short* Qg  = (unsigned short*)ws;                 //  2,048,000 B
  unsigned short* Wc2 = (unsigned short*)(ws + 2048000);     //    131,072 B
  unsigned short* Wq2 = (unsigned short*)(ws + 2179072);     //     32,768 B
  float* ul = (float*)(ws + 2211840);                        //  4,096,000 B
  float* Hn = (float*)(ws + 6307840);                        //  4,096,000 B
  float* Z  = (float*)(ws + 10403840);                       // 16,384,000 B

  conv_weights_kernel<<<320, 256, 0, stream>>>(W_K, W_V, W_Q, Wc2, Wq2);
  q_gemm_kernel<<<(NTOK + 127)/128, 512, 0, stream>>>(h_v, Wq2, Qg);
  kvattn_kernel<<<NTOK/4, 512, 0, stream>>>(h_e, Wc2, Qg, mask_attend, ul);
  wo_ln_kernel<<<NTOK/32, 256, 0, stream>>>(ul, W_O, h_v, gain0, bias0, Hn);
  ffn1_kernel<<<dim3(NTOK/32, TDFF/128), 256, 0, stream>>>(Hn, W_in, b_in, Z);
  ffn2_kernel<<<NTOK/32, 256, 0, stream>>>(Z, W_out, b_out, Hn, gain1, bias1,
                                           mask_v, out);
}

// Round 8
// 91.316 us; speedup vs baseline: 2.0527x; 1.5968x over previous
//
#include <hip/hip_runtime.h>
#include <math.h>

#define TK 30
#define TH 128
#define TNIN 256
#define TDFF 512
#define NTOK 8000
#define ROWP 264   // KVs row stride in u16

typedef __attribute__((ext_vector_type(8))) short short8v;
typedef __attribute__((ext_vector_type(4))) short short4v;
typedef __attribute__((ext_vector_type(4))) float f32x4;

constexpr float LN_EPS = 1e-6f;
constexpr float NEG_INF = -3.402823466e38f;
constexpr float INV_SQRT_D = 0.17677669529663687f;  // 1/sqrt(32)

static __device__ __forceinline__ unsigned short f2bf(float f) {
  unsigned u = __float_as_uint(f);
  u = u + 0x7fffu + ((u >> 16) & 1u);
  return (unsigned short)(u >> 16);
}
static __device__ __forceinline__ float bf2f(unsigned short s) {
  return __uint_as_float(((unsigned)s) << 16);
}
static __device__ __forceinline__ void gload16(const void* gsrc, void* ldst) {
  __builtin_amdgcn_global_load_lds(
      (const __attribute__((address_space(1))) unsigned int*)gsrc,
      (__attribute__((address_space(3))) unsigned int*)ldst, 16, 0, 0);
}

// ---------------------------------------------------------------------------
// K0: weight prep.  Frag-linear bf16 layouts (verified pattern):
//   elem ((ks*NF + n)*64 + lane)*8 + j  =  W[n*16+(lane&15)][ks*32+(lane>>4)*8+j]
//  idx <  65536 : Wc2 = [W_K;W_V]  (NF=16, K=256)
//  < 81920      : Wq2 = W_Q        (NF=8,  K=128)
//  < 147456     : Wi2 = W_in       (NF=32, K=128)
//  else         : Wo2 = W_out      (NF=8,  K=512)
// ---------------------------------------------------------------------------
__global__ void conv_weights_kernel(const float* __restrict__ W_K,
                                    const float* __restrict__ W_V,
                                    const float* __restrict__ W_Q,
                                    const float* __restrict__ W_in,
                                    const float* __restrict__ W_out,
                                    unsigned short* __restrict__ Wc2,
                                    unsigned short* __restrict__ Wq2,
                                    unsigned short* __restrict__ Wi2,
                                    unsigned short* __restrict__ Wo2)
{
  int idx = blockIdx.x * 256 + threadIdx.x;   // 0..212991
  if (idx < 65536) {
    int e = idx >> 3, j = idx & 7;
    int kk = e >> 10, n = (e >> 6) & 15, lane = e & 63;
    int r = n*16 + (lane & 15);
    int c = kk*32 + (lane >> 4)*8 + j;
    float v = (r < TH) ? W_K[(size_t)r*TNIN + c] : W_V[(size_t)(r-TH)*TNIN + c];
    Wc2[idx] = f2bf(v);
  } else if (idx < 81920) {
    int i2 = idx - 65536;
    int e = i2 >> 3, j = i2 & 7;
    int kk = e >> 9, n = (e >> 6) & 7, lane = e & 63;
    int r = n*16 + (lane & 15);
    int c = kk*32 + (lane >> 4)*8 + j;
    Wq2[i2] = f2bf(W_Q[(size_t)r*TH + c]);
  } else if (idx < 147456) {
    int i3 = idx - 81920;
    int e = i3 >> 3, j = i3 & 7;
    int ks = e >> 11, n = (e >> 6) & 31, lane = e & 63;
    int r = n*16 + (lane & 15);
    int c = ks*32 + (lane >> 4)*8 + j;
    Wi2[i3] = f2bf(W_in[(size_t)r*TH + c]);
  } else {
    int i4 = idx - 147456;
    int e = i4 >> 3, j = i4 & 7;
    int ks = e >> 9, n = (e >> 6) & 7, lane = e & 63;
    int r = n*16 + (lane & 15);
    int c = ks*32 + (lane >> 4)*8 + j;
    Wo2[i4] = f2bf(W_out[(size_t)r*TDFF + c]);
  }
}

// ---------------------------------------------------------------------------
// K1: fused KV-GEMM + attention core (R7 core; A-prefetch deepened to dist-3).
// grid = 2000 x 512 thr, 2 blocks/CU.
// ---------------------------------------------------------------------------
__global__ __launch_bounds__(512, 4) void kvattn_kernel(
    const float* __restrict__ A, const unsigned short* __restrict__ Wc2,
    const unsigned short* __restrict__ Qg, const float* __restrict__ mask_attend,
    float* __restrict__ ul)
{
  const int tid  = threadIdx.x;
  const int wave = tid >> 6;
  const int lane = tid & 63;
  const int lm   = lane & 15;
  const int lgp  = lane >> 4;
  const int mh   = wave >> 2;   // 0..1
  const int nq   = wave & 3;    // 0..3

  __shared__ __align__(16) char smem[69632];
  unsigned short* Bl  = (unsigned short*)smem;          // [3][8192]
  unsigned short* Al  = (unsigned short*)(smem + 49152);// [2][128][40]
  unsigned short* KVs = (unsigned short*)smem;          // [128][264] overlay
  float* att = (float*)(smem + 67584);                  // [4][4][32]

  const int rowa = tid >> 2, cga = tid & 3;
  const int rowc = (rowa > 119) ? 119 : rowa;
  const float* aptr = A + ((size_t)blockIdx.x*120 + rowc)*TNIN + cga*8;

  #define ISSUE_B(K)                                                             \
    { gload16(Wc2 + (size_t)(K)*8192 + tid*8,       &Bl[((K)%3)*8192 + tid*8]);  \
      gload16(Wc2 + (size_t)(K)*8192 + (tid+512)*8, &Bl[((K)%3)*8192 + (tid+512)*8]); }

  #define WRITE_A(K, S)                                                     \
    { short8v w;                                                            \
      w[0]=(short)f2bf(ra[S][0].x); w[1]=(short)f2bf(ra[S][0].y);           \
      w[2]=(short)f2bf(ra[S][0].z); w[3]=(short)f2bf(ra[S][0].w);           \
      w[4]=(short)f2bf(ra[S][1].x); w[5]=(short)f2bf(ra[S][1].y);           \
      w[6]=(short)f2bf(ra[S][1].z); w[7]=(short)f2bf(ra[S][1].w);           \
      *(short8v*)&Al[(((K)&1)*128 + rowa)*40 + cga*8] = w; }

  float4 ra[3][2];
  f32x4 acc[4][4] = {};

  // prologue: rA(0); B(0); B(1); rA(1); rA(2); write A(0)
  ra[0][0] = *(const float4*)(aptr + 0);
  ra[0][1] = *(const float4*)(aptr + 4);
  ISSUE_B(0);
  ISSUE_B(1);
  ra[1][0] = *(const float4*)(aptr + 32);
  ra[1][1] = *(const float4*)(aptr + 36);
  ra[2][0] = *(const float4*)(aptr + 64);
  ra[2][1] = *(const float4*)(aptr + 68);
  WRITE_A(0, 0);

  #pragma unroll
  for (int k = 0; k < 8; ++k) {
    // in-order queue audit (R8): k<=5 -> 6 outstanding allowed, k==6 -> 4, k==7 -> 0
    if (k == 7)      asm volatile("s_waitcnt vmcnt(0)" ::: "memory");
    else if (k == 6) asm volatile("s_waitcnt vmcnt(4)" ::: "memory");
    else             asm volatile("s_waitcnt vmcnt(6)" ::: "memory");
    __builtin_amdgcn_s_barrier();

    if (k < 6) ISSUE_B(k+2);
    if (k < 5) {   // A prefetch distance 3
      ra[k%3][0] = *(const float4*)(aptr + (k+3)*32);
      ra[k%3][1] = *(const float4*)(aptr + (k+3)*32 + 4);
    }

    short8v af[4];
    #pragma unroll
    for (int m = 0; m < 4; ++m)
      af[m] = *(const short8v*)&Al[((k&1)*128 + mh*64 + m*16 + lm)*40 + lgp*8];

    #pragma unroll
    for (int n = 0; n < 4; ++n) {
      short8v b = *(const short8v*)&Bl[(k%3)*8192 + ((nq*4 + n)*64 + lane)*8];
      #pragma unroll
      for (int m = 0; m < 4; ++m)
        acc[m][n] = __builtin_amdgcn_mfma_f32_16x16x32_bf16(b, af[m], acc[m][n], 0, 0, 0);
    }

    if (k < 7) WRITE_A(k+1, (k+1)%3);
  }
  #undef ISSUE_B
  #undef WRITE_A

  __syncthreads();   // all Bl/Al reads done before KVs overlay

  #pragma unroll
  for (int m = 0; m < 4; ++m) {
    int row = mh*64 + m*16 + lm;
    #pragma unroll
    for (int n = 0; n < 4; ++n) {
      int col = nq*64 + n*16 + lgp*4;
      short4v p;
      p[0]=(short)f2bf(acc[m][n][0]); p[1]=(short)f2bf(acc[m][n][1]);
      p[2]=(short)f2bf(acc[m][n][2]); p[3]=(short)f2bf(acc[m][n][3]);
      *(short4v*)&KVs[row*ROWP + col] = p;
    }
  }
  __syncthreads();

  // ---- logits + masked softmax ----
  {
    int tok = tid >> 7, h = (tid >> 5) & 3, k = tid & 31;
    int gtok = blockIdx.x*4 + tok;
    float s = 0.f;
    float ma = 0.f;
    if (k < TK) {
      const unsigned short* qp = Qg + (size_t)gtok*TH + h*32;
      const unsigned short* kp = &KVs[(tok*TK + k)*ROWP + h*32];
      #pragma unroll
      for (int j = 0; j < 4; ++j) {
        short8v qf = *(const short8v*)(qp + j*8);
        short8v kf = *(const short8v*)(kp + j*8);
        #pragma unroll
        for (int e = 0; e < 8; ++e)
          s += bf2f((unsigned short)qf[e]) * bf2f((unsigned short)kf[e]);
      }
      ma = mask_attend[(size_t)gtok*TK + k];
    }
    bool ok = (k < TK) && (ma > 0.f);
    float val = ok ? s * INV_SQRT_D : NEG_INF;
    float mm = val;
    #pragma unroll
    for (int d = 16; d >= 1; d >>= 1) mm = fmaxf(mm, __shfl_xor(mm, d, 32));
    float e = ok ? expf(val - mm) : 0.f;
    float ss = e;
    #pragma unroll
    for (int d = 16; d >= 1; d >>= 1) ss += __shfl_xor(ss, d, 32);
    att[(tok*4 + h)*32 + k] = e / ss;
  }
  __syncthreads();

  // ---- PV ----
  {
    int tok = tid >> 7, c = tid & 127;
    int gtok = blockIdx.x*4 + tok;
    const float* ar = &att[(tok*4 + (c >> 5))*32];
    const unsigned short* vb = &KVs[tok*TK*ROWP + TH + c];
    float u = 0.f;
    #pragma unroll
    for (int k = 0; k < TK; ++k)
      u += ar[k] * bf2f(vb[k*ROWP]);
    ul[(size_t)gtok*TH + c] = u;
  }
}

// ---------------------------------------------------------------------------
// K1b: Q = h_v @ W_Q^T  (verbatim R7, verified)
// ---------------------------------------------------------------------------
__global__ __launch_bounds__(512, 4) void q_gemm_kernel(
    const float* __restrict__ h_v, const unsigned short* __restrict__ Wq2,
    unsigned short* __restrict__ Qg)
{
  const int m0   = blockIdx.x * 128;
  const int tid  = threadIdx.x;
  const int wave = tid >> 6;
  const int lane = tid & 63;
  const int lm   = lane & 15;
  const int lgp  = lane >> 4;
  const int mh   = wave >> 2;
  const int nq   = wave & 3;

  __shared__ __align__(16) char smem[53248];
  unsigned short* Bq = (unsigned short*)smem;           // [16384]
  unsigned short* Al = (unsigned short*)(smem + 32768); // [2][128][40]
  unsigned short* Ct = (unsigned short*)smem;           // [128][136] overlay

  const int rowa = tid >> 2, cga = tid & 3;
  int rc = m0 + rowa; if (rc > NTOK-1) rc = NTOK-1;
  const float* aptr = h_v + (size_t)rc*TH + cga*8;

  #define WRITE_A(K, S)                                                     \
    { short8v w;                                                            \
      w[0]=(short)f2bf(ra[S][0].x); w[1]=(short)f2bf(ra[S][0].y);           \
      w[2]=(short)f2bf(ra[S][0].z); w[3]=(short)f2bf(ra[S][0].w);           \
      w[4]=(short)f2bf(ra[S][1].x); w[5]=(short)f2bf(ra[S][1].y);           \
      w[6]=(short)f2bf(ra[S][1].z); w[7]=(short)f2bf(ra[S][1].w);           \
      *(short8v*)&Al[(((K)&1)*128 + rowa)*40 + cga*8] = w; }

  float4 ra[2][2];
  f32x4 acc[4][2] = {};

  ra[0][0] = *(const float4*)(aptr + 0);
  ra[0][1] = *(const float4*)(aptr + 4);
  #pragma unroll
  for (int p = 0; p < 4; ++p)
    gload16(Wq2 + (size_t)(tid + p*512)*8, &Bq[(tid + p*512)*8]);
  ra[1][0] = *(const float4*)(aptr + 32);
  ra[1][1] = *(const float4*)(aptr + 36);
  WRITE_A(0, 0);

  #pragma unroll
  for (int k = 0; k < 4; ++k) {
    if (k == 0) asm volatile("s_waitcnt vmcnt(2)" ::: "memory");
    __builtin_amdgcn_s_barrier();

    if (k < 2) {
      ra[k&1][0] = *(const float4*)(aptr + (k+2)*32);
      ra[k&1][1] = *(const float4*)(aptr + (k+2)*32 + 4);
    }

    short8v af[4];
    #pragma unroll
    for (int m = 0; m < 4; ++m)
      af[m] = *(const short8v*)&Al[((k&1)*128 + mh*64 + m*16 + lm)*40 + lgp*8];

    #pragma unroll
    for (int n = 0; n < 2; ++n) {
      short8v b = *(const short8v*)&Bq[((k*8 + nq*2 + n)*64 + lane)*8];
      #pragma unroll
      for (int m = 0; m < 4; ++m)
        acc[m][n] = __builtin_amdgcn_mfma_f32_16x16x32_bf16(b, af[m], acc[m][n], 0, 0, 0);
    }

    if (k < 3) WRITE_A(k+1, (k+1)&1);
  }
  #undef WRITE_A

  __syncthreads();
  #pragma unroll
  for (int m = 0; m < 4; ++m) {
    int row = mh*64 + m*16 + lm;
    #pragma unroll
    for (int n = 0; n < 2; ++n) {
      int col = nq*32 + n*16 + lgp*4;
      short4v p;
      p[0]=(short)f2bf(acc[m][n][0]); p[1]=(short)f2bf(acc[m][n][1]);
      p[2]=(short)f2bf(acc[m][n][2]); p[3]=(short)f2bf(acc[m][n][3]);
      *(short4v*)&Ct[row*136 + col] = p;
    }
  }
  __syncthreads();
  #pragma unroll
  for (int p = 0; p < 4; ++p) {
    int t = p*512 + tid;
    int row = t >> 4, cg = t & 15;
    if (m0 + row < NTOK)
      *(short8v*)&Qg[(size_t)(m0 + row)*TH + cg*8] =
          *(const short8v*)&Ct[row*136 + cg*8];
  }
}

// ---------------------------------------------------------------------------
// K2: Hn = LN0(h_v + ul @ W_O^T)   (verbatim R7, verified)
// ---------------------------------------------------------------------------
__global__ __launch_bounds__(256) void wo_ln_kernel(
    const float* __restrict__ ul, const float* __restrict__ W_O,
    const float* __restrict__ h_v, const float* __restrict__ gain0,
    const float* __restrict__ bias0, float* __restrict__ Hn)
{
  const int tid  = threadIdx.x;
  const int tok0 = blockIdx.x * 32;
  __shared__ float Aa[32][128];
  __shared__ float Wt[128][128];

  for (int t = tid; t < 32*32; t += 256) {
    int row = t >> 5, i4 = t & 31;
    *(float4*)&Aa[row][i4*4] = *(const float4*)&ul[(size_t)(tok0+row)*TH + i4*4];
  }
  for (int t = tid; t < 128*32; t += 256) {
    int f = t & 127, i4 = t >> 7;
    float4 w = *(const float4*)&W_O[(size_t)f*TH + i4*4];
    Wt[i4*4+0][f]=w.x; Wt[i4*4+1][f]=w.y; Wt[i4*4+2][f]=w.z; Wt[i4*4+3][f]=w.w;
  }
  __syncthreads();

  const int tokg = tid>>5, colg = tid&31;
  float acc[4][4] = {};
  for (int i = 0; i < TH; i += 4){
    float a[4][4];
    #pragma unroll
    for (int r=0;r<4;r++){
      float4 tv=*(const float4*)&Aa[tokg*4+r][i];
      a[r][0]=tv.x;a[r][1]=tv.y;a[r][2]=tv.z;a[r][3]=tv.w;
    }
    #pragma unroll
    for (int d=0; d<4; ++d){
      float4 wv = *(const float4*)&Wt[i+d][colg*4];
      #pragma unroll
      for (int r=0;r<4;r++){
        acc[r][0]+=a[r][d]*wv.x; acc[r][1]+=a[r][d]*wv.y;
        acc[r][2]+=a[r][d]*wv.z; acc[r][3]+=a[r][d]*wv.w;
      }
    }
  }

  float4 g  = *(const float4*)&gain0[colg*4];
  float4 bb = *(const float4*)&bias0[colg*4];
  #pragma unroll
  for (int r=0;r<4;r++){
    int tok = tok0 + tokg*4 + r;
    float4 hv = *(const float4*)&h_v[(size_t)tok*TH + colg*4];
    float x0 = acc[r][0]+hv.x;
    float x1 = acc[r][1]+hv.y;
    float x2 = acc[r][2]+hv.z;
    float x3 = acc[r][3]+hv.w;
    float s1 = x0+x1+x2+x3;
    float s2 = x0*x0+x1*x1+x2*x2+x3*x3;
    #pragma unroll
    for (int m=16;m>=1;m>>=1){ s1 += __shfl_xor(s1,m,32); s2 += __shfl_xor(s2,m,32); }
    float mu  = s1*(1.f/128.f);
    float var = (s2 - 128.f*mu*mu)*(1.f/127.f);
    float inv = 1.f/(sqrtf(var+LN_EPS)+LN_EPS);
    float4 y;
    y.x = g.x*(x0-mu)*inv + bb.x;
    y.y = g.y*(x1-mu)*inv + bb.y;
    y.z = g.z*(x2-mu)*inv + bb.z;
    y.w = g.w*(x3-mu)*inv + bb.w;
    *(float4*)&Hn[(size_t)tok*TH + colg*4] = y;
  }
}

// ---------------------------------------------------------------------------
// K3: fused FFN (MFMA bf16): out = mask_v * LN1(Hn + relu(Hn@W_in^T+b_in)@W_out^T + b_out)
// grid = 250 x 256 thr (4 waves). 32 tokens/block.
// GEMM1: M=32(2mf) N=512(8nf/wave) K=128(4 ks);  GEMM2: M=32 N=128(2nf/wave) K=512(16 ks).
// Swapped-operand MFMA throughout (verified mapping).
// ---------------------------------------------------------------------------
__global__ __launch_bounds__(256) void ffn_fused_kernel(
    const float* __restrict__ Hn, const unsigned short* __restrict__ Wi2,
    const unsigned short* __restrict__ Wo2,
    const float* __restrict__ b_in, const float* __restrict__ b_out,
    const float* __restrict__ gain1, const float* __restrict__ bias1,
    const float* __restrict__ mask_v, float* __restrict__ out)
{
  const int tid  = threadIdx.x;
  const int tok0 = blockIdx.x * 32;
  const int wave = tid >> 6;
  const int lane = tid & 63;
  const int lm   = lane & 15;
  const int lgp  = lane >> 4;

  __shared__ __align__(16) char bst_mem[32768];          // B stage; Xs overlay
  __shared__ __align__(16) unsigned short At[32][136];   // Hn bf16
  __shared__ __align__(16) unsigned short Zs[32][520];   // Z bf16
  __shared__ float bin[512];
  unsigned short* Bst = (unsigned short*)bst_mem;
  float* Xs = (float*)bst_mem;                           // [32][132] overlay

  // ---- stage At (Hn -> bf16) and bin ----
  for (int t = tid; t < 1024; t += 256) {
    int row = t >> 5, q = t & 31;
    float4 v = *(const float4*)&Hn[(size_t)(tok0+row)*TH + q*4];
    short4v w;
    w[0]=(short)f2bf(v.x); w[1]=(short)f2bf(v.y);
    w[2]=(short)f2bf(v.z); w[3]=(short)f2bf(v.w);
    *(short4v*)&At[row][q*4] = w;
  }
  if (tid < 128) *(float4*)&bin[tid*4] = *(const float4*)&b_in[tid*4];

  // ---- GEMM1: Z = relu(Hn @ W_in^T + b_in) ----
  f32x4 acc1[2][8] = {};
  #pragma unroll
  for (int ks = 0; ks < 4; ++ks) {
    #pragma unroll
    for (int p = 0; p < 8; ++p)
      gload16(Wi2 + (size_t)ks*16384 + (tid + p*256)*8, &Bst[(tid + p*256)*8]);
    asm volatile("s_waitcnt vmcnt(0)" ::: "memory");
    __syncthreads();   // B ready + (ks==0) At/bin ds_writes visible

    short8v a0 = *(const short8v*)&At[lm]     [ks*32 + lgp*8];
    short8v a1 = *(const short8v*)&At[16 + lm][ks*32 + lgp*8];
    #pragma unroll
    for (int n = 0; n < 8; ++n) {
      short8v b = *(const short8v*)&Bst[((wave*8 + n)*64 + lane)*8];
      acc1[0][n] = __builtin_amdgcn_mfma_f32_16x16x32_bf16(b, a0, acc1[0][n], 0, 0, 0);
      acc1[1][n] = __builtin_amdgcn_mfma_f32_16x16x32_bf16(b, a1, acc1[1][n], 0, 0, 0);
    }
    __syncthreads();   // all reads done before next stage overwrites Bst
  }

  // Z writeout: row = m*16+lm, cols = (wave*8+n)*16 + lgp*4 + r; relu+bias
  #pragma unroll
  for (int m = 0; m < 2; ++m) {
    int row = m*16 + lm;
    #pragma unroll
    for (int n = 0; n < 8; ++n) {
      int col = (wave*8 + n)*16 + lgp*4;
      float4 bv = *(const float4*)&bin[col];
      short4v p;
      p[0]=(short)f2bf(fmaxf(acc1[m][n][0] + bv.x, 0.f));
      p[1]=(short)f2bf(fmaxf(acc1[m][n][1] + bv.y, 0.f));
      p[2]=(short)f2bf(fmaxf(acc1[m][n][2] + bv.z, 0.f));
      p[3]=(short)f2bf(fmaxf(acc1[m][n][3] + bv.w, 0.f));
      *(short4v*)&Zs[row][col] = p;
    }
  }
  __syncthreads();

  // ---- GEMM2: Y = Zs @ W_out^T  (stage 2 k-steps per sync) ----
  f32x4 acc2[2][2] = {};
  #pragma unroll
  for (int ks2 = 0; ks2 < 8; ++ks2) {
    #pragma unroll
    for (int p = 0; p < 4; ++p)
      gload16(Wo2 + (size_t)ks2*8192 + (tid + p*256)*8, &Bst[(tid + p*256)*8]);
    asm volatile("s_waitcnt vmcnt(0)" ::: "memory");
    __syncthreads();

    #pragma unroll
    for (int s = 0; s < 2; ++s) {
      int ks = ks2*2 + s;
      short8v a0 = *(const short8v*)&Zs[lm]     [ks*32 + lgp*8];
      short8v a1 = *(const short8v*)&Zs[16 + lm][ks*32 + lgp*8];
      #pragma unroll
      for (int n = 0; n < 2; ++n) {
        short8v b = *(const short8v*)&Bst[(s*4096) + ((wave*2 + n)*64 + lane)*8];
        acc2[0][n] = __builtin_amdgcn_mfma_f32_16x16x32_bf16(b, a0, acc2[0][n], 0, 0, 0);
        acc2[1][n] = __builtin_amdgcn_mfma_f32_16x16x32_bf16(b, a1, acc2[1][n], 0, 0, 0);
      }
    }
    __syncthreads();
  }

  // x = Y + b_out + Hn(f32 residual) -> Xs (overlay on Bst; all B reads done)
  #pragma unroll
  for (int m = 0; m < 2; ++m) {
    int row = m*16 + lm;
    #pragma unroll
    for (int n = 0; n < 2; ++n) {
      int col = (wave*2 + n)*16 + lgp*4;
      float4 bo = *(const float4*)&b_out[col];
      float4 hn = *(const float4*)&Hn[(size_t)(tok0+row)*TH + col];
      float4 x;
      x.x = acc2[m][n][0] + bo.x + hn.x;
      x.y = acc2[m][n][1] + bo.y + hn.y;
      x.z = acc2[m][n][2] + bo.z + hn.z;
      x.w = acc2[m][n][3] + bo.w + hn.w;
      *(float4*)&Xs[(size_t)row*132 + col] = x;
    }
  }
  __syncthreads();

  // ---- LN1 + mask (ffn2-verbatim reduction over Xs) ----
  {
    const int tokg = tid >> 5, colg = tid & 31;
    float4 g  = *(const float4*)&gain1[colg*4];
    float4 bb = *(const float4*)&bias1[colg*4];
    float4 bo; (void)bo;
    #pragma unroll
    for (int r = 0; r < 4; ++r) {
      int tok = tok0 + tokg*4 + r;
      float4 xv = *(const float4*)&Xs[(size_t)(tokg*4 + r)*132 + colg*4];
      float x0 = xv.x, x1 = xv.y, x2 = xv.z, x3 = xv.w;
      float s1 = x0+x1+x2+x3;
      float s2 = x0*x0+x1*x1+x2*x2+x3*x3;
      #pragma unroll
      for (int m = 16; m >= 1; m >>= 1) { s1 += __shfl_xor(s1,m,32); s2 += __shfl_xor(s2,m,32); }
      float mu  = s1*(1.f/128.f);
      float var = (s2 - 128.f*mu*mu)*(1.f/127.f);
      float inv = 1.f/(sqrtf(var+LN_EPS)+LN_EPS);
      float mv  = mask_v[tok];
      float4 y;
      y.x = mv*(g.x*(x0-mu)*inv + bb.x);
      y.y = mv*(g.y*(x1-mu)*inv + bb.y);
      y.z = mv*(g.z*(x2-mu)*inv + bb.z);
      y.w = mv*(g.w*(x3-mu)*inv + bb.w);
      *(float4*)&out[(size_t)tok*TH + colg*4] = y;
    }
  }
}

// ---------------------------------------------------------------------------
extern "C" void kernel_launch(void* const* d_in, const int* in_sizes, int n_in,
                              void* d_out, int out_size, void* d_ws, size_t ws_size,
                              hipStream_t stream)
{
  const float* h_v         = (const float*)d_in[0];
  const float* h_e         = (const float*)d_in[1];
  const float* mask_v      = (const float*)d_in[2];
  const float* mask_attend = (const float*)d_in[3];
  const float* W_Q   = (const float*)d_in[4];
  const float* W_K   = (const float*)d_in[5];
  const float* W_V   = (const float*)d_in[6];
  const float* W_O   = (const float*)d_in[7];
  const float* gain0 = (const float*)d_in[8];
  const float* bias0 = (const float*)d_in[9];
  const float* gain1 = (const float*)d_in[10];
  const float* bias1 = (const float*)d_in[11];
  const float* W_in  = (const float*)d_in[12];
  const float* b_in  = (const float*)d_in[13];
  const float* W_out = (const float*)d_in[14];
  const float* b_out = (const float*)d_in[15];

  float* out = (float*)d_out;
  char* ws = (char*)d_ws;
  unsigned short* Qg  = (unsigned short*)ws;                 //  2,048,000 B
  unsigned short* Wc2 = (unsigned short*)(ws + 2048000);     //    131,072 B
  unsigned short* Wq2 = (unsigned short*)(ws + 2179072);     //     32,768 B
  unsigned short* Wi2 = (unsigned short*)(ws + 2211840);     //    131,072 B
  unsigned short* Wo2 = (unsigned short*)(ws + 2342912);     //    131,072 B
  float* ul = (float*)(ws + 2473984);                        //  4,096,000 B
  float* Hn = (float*)(ws + 6569984);                        //  4,096,000 B

  conv_weights_kernel<<<832, 256, 0, stream>>>(W_K, W_V, W_Q, W_in, W_out,
                                               Wc2, Wq2, Wi2, Wo2);
  q_gemm_kernel<<<(NTOK + 127)/128, 512, 0, stream>>>(h_v, Wq2, Qg);
  kvattn_kernel<<<NTOK/4, 512, 0, stream>>>(h_e, Wc2, Qg, mask_attend, ul);
  wo_ln_kernel<<<NTOK/32, 256, 0, stream>>>(ul, W_O, h_v, gain0, bias0, Hn);
  ffn_fused_kernel<<<NTOK/32, 256, 0, stream>>>(Hn, Wi2, Wo2, b_in, b_out,
                                                gain1, bias1, mask_v, out);
}